// Round 9
// baseline (471.567 us; speedup 1.0000x reference)
//
#include <hip/hip_runtime.h>
#include <hip/hip_fp16.h>

#define H1 15
#define H2 81
#define FXS 10
#define FXT 5
#define FE 10
#define FU 10
#define SCAN_B 1024
#define TBE 1024              // k_edge_mfma2 threads (16 waves)
#define NPBLK 64              // nodes per k_moments3 block

typedef _Float16 half4 __attribute__((ext_vector_type(4)));
typedef float floatx4 __attribute__((ext_vector_type(4)));
typedef unsigned int uint;
typedef unsigned short ushort;

// ---------------- per-node CSR build (proven round 2) ----------------

__global__ void k_hist(const int* __restrict__ src, int* __restrict__ cnt, int E) {
    int e = blockIdx.x * blockDim.x + threadIdx.x;
    if (e < E) atomicAdd(&cnt[src[e]], 1);
}

__global__ void k_scan1(const int* __restrict__ cnt, int* __restrict__ offs,
                        int* __restrict__ bsum, int NSs) {
    __shared__ int lds[SCAN_B];
    int t = threadIdx.x, g = blockIdx.x * SCAN_B + t;
    int v = (g < NSs) ? cnt[g] : 0;
    lds[t] = v;
    __syncthreads();
    for (int d = 1; d < SCAN_B; d <<= 1) {
        int add = (t >= d) ? lds[t - d] : 0;
        __syncthreads();
        lds[t] += add;
        __syncthreads();
    }
    int incl = lds[t];
    if (g < NSs) offs[g] = incl - v;
    if (t == SCAN_B - 1) bsum[blockIdx.x] = incl;
}

__global__ void k_scan2(int* __restrict__ bsum, int nb) {
    __shared__ int lds[SCAN_B];
    int t = threadIdx.x;
    int v = (t < nb) ? bsum[t] : 0;
    lds[t] = v;
    __syncthreads();
    for (int d = 1; d < SCAN_B; d <<= 1) {
        int add = (t >= d) ? lds[t - d] : 0;
        __syncthreads();
        lds[t] += add;
        __syncthreads();
    }
    if (t < nb) bsum[t] = lds[t] - v;
}

__global__ void k_scan3(int* __restrict__ offs, const int* __restrict__ bsum, int NSs) {
    int g = blockIdx.x * SCAN_B + threadIdx.x;
    if (g < NSs) offs[g] += bsum[blockIdx.x];
}

// ---------------- edge-order MFMA MLP, per-thread 32B record scatter ----------------
// Per wave: 64 edges. lds_f row = one edge's 16 fp16 features (40B stride, bank-clean).
// MFMA groups read 16 rows, compute both layers, write outputs back into the SAME
// rows/cols (wave-private rows -> per-wave in-order LDS, NO barriers anywhere).
// Then thread t reads its own row t and writes one full 32B record to the
// node-sorted position -> single-thread 32B scatter = amplification-free (round-2 evidence).

__global__ __launch_bounds__(TBE, 8) void k_edge_mfma2(
    const float* __restrict__ x_t, const float* __restrict__ ea,
    const float* __restrict__ W1, const float* __restrict__ b1,
    const float* __restrict__ W2, const float* __restrict__ b2,
    const int* __restrict__ src, const int* __restrict__ tgt,
    const int* __restrict__ offs, int* __restrict__ cursor,
    uint* __restrict__ buf, int E)
{
    __shared__ ushort lds_f[TBE][20];          // 40 KB

    int t = threadIdx.x;
    int lane = t & 63, w = t >> 6;
    int e = blockIdx.x * TBE + t;
    bool valid = (e < E);
    int em = lane & 15;
    int kb = (lane >> 4) << 2;

    // resident weight/bias fragments (layout HW-verified rounds 4-8)
    half4 a1f, a2f;
    floatx4 c1f, c2f;
#pragma unroll
    for (int i = 0; i < 4; i++) {
        int kk = kb + i;
        bool wv = (kk < H1) && (em < H1);
        a1f[i] = wv ? (_Float16)W1[kk * H1 + em] : (_Float16)0.f;
        a2f[i] = wv ? (_Float16)W2[kk * H1 + em] : (_Float16)0.f;
        c1f[i] = (kk < H1) ? b1[kk] : 0.f;
        c2f[i] = (kk < H1) ? b2[kk] : 0.f;
    }

    int pos = 0;
    if (valid) {
        int sv = src[e], tg = tgt[e];
        pos = offs[sv] + atomicAdd(&cursor[sv], 1);   // consumed only at final store
        float f[16];
        const float* xr = x_t + (size_t)tg * FXT;
#pragma unroll
        for (int i = 0; i < FXT; i++) f[i] = xr[i];
        const float2* er = (const float2*)(ea + (size_t)e * FE);
#pragma unroll
        for (int i = 0; i < FE / 2; i++) {
            float2 v = er[i];
            f[FXT + 2 * i] = v.x;
            f[FXT + 2 * i + 1] = v.y;
        }
        f[15] = 0.f;
#pragma unroll
        for (int c = 0; c < 4; c++) {
            half4 hv;
#pragma unroll
            for (int i = 0; i < 4; i++) hv[i] = (_Float16)f[c * 4 + i];
            *(half4*)&lds_f[t][c * 4] = hv;
        }
    }
    // no barrier: each wave reads/writes only rows [w*64, w*64+64)

#pragma unroll
    for (int g = 0; g < 4; g++) {
        int tt = w * 64 + g * 16 + em;               // edge row for column em
        half4 bf = *(const half4*)&lds_f[tt][kb];
        floatx4 d1 = __builtin_amdgcn_mfma_f32_16x16x16f16(a1f, bf, c1f, 0, 0, 0);
        half4 h;
#pragma unroll
        for (int i = 0; i < 4; i++) {
            float x = d1[i];
            x = fmaxf(x, 0.1f * x);
            h[i] = (_Float16)x;
        }
        floatx4 d2 = __builtin_amdgcn_mfma_f32_16x16x16f16(a2f, h, c2f, 0, 0, 0);
        half4 ov;                                     // rows kb..kb+3 of edge tt
#pragma unroll
        for (int i = 0; i < 4; i++) ov[i] = (_Float16)d2[i];
        *(half4*)&lds_f[tt][kb] = ov;                 // row 15 slot = exact 0 (padded W2/b2)
    }

    if (valid) {
        // gather own full record (written by own wave; per-wave LDS is in-order)
        uint2 q0 = *(uint2*)&lds_f[t][0];
        uint2 q1 = *(uint2*)&lds_f[t][4];
        uint2 q2 = *(uint2*)&lds_f[t][8];
        uint2 q3 = *(uint2*)&lds_f[t][12];
        uint* dst = buf + (size_t)pos * 8;
        *(uint4*)(dst)     = make_uint4(q0.x, q0.y, q1.x, q1.y);
        *(uint4*)(dst + 4) = make_uint4(q2.x, q2.y, q3.x, q3.y);
    }
}

// ---------------- node-sorted streaming moments + node MLP ----------------
// Records for node s occupy [offs[s], offs[s]+cnt[s]) -- contiguous. A wave's
// 16-edge group reads one contiguous 512B window: lane (em,kb) reads 8B at
// record (start+g*16+em), halves kb..kb+3 -> perfectly coalesced.

__global__ __launch_bounds__(256, 4) void k_moments3(
    const float* __restrict__ x_s, const float* __restrict__ u,
    const float* __restrict__ W3, const float* __restrict__ b3,
    const float* __restrict__ W4, const float* __restrict__ b4,
    const int* __restrict__ batch_s,
    const int* __restrict__ cnt, const int* __restrict__ offs,
    const uint* __restrict__ buf,
    float* __restrict__ out, int NSs)
{
    __shared__ float sW3[H2 * FXS], sb3[FXS], sW4[FXS * FXS], sb4[FXS];
    __shared__ float feat[NPBLK][H2 + 3];
    __shared__ float l1s[NPBLK][12];

    int t = threadIdx.x;
    for (int i = t; i < H2 * FXS; i += 256) sW3[i] = W3[i];
    for (int i = t; i < FXS * FXS; i += 256) sW4[i] = W4[i];
    if (t < FXS) { sb3[t] = b3[t]; sb4[t] = b4[t]; }
    __syncthreads();

    int lane = t & 63, wv = t >> 6;
    int em = lane & 15;
    int kb = (lane >> 4) << 2;
    int nb = blockIdx.x * NPBLK;

    for (int li = wv; li < NPBLK; li += 4) {
        int s = nb + li;
        if (s >= NSs) break;                          // no barriers inside loop
        int n = cnt[s], start = offs[s];
        int ng = (n + 15) >> 4;
        const uint* rp = buf + (size_t)start * 8;

        float s1[4] = {0.f, 0.f, 0.f, 0.f};
        float s2[4] = {0.f, 0.f, 0.f, 0.f};
        float s3[4] = {0.f, 0.f, 0.f, 0.f};
        float s4[4] = {0.f, 0.f, 0.f, 0.f};

        for (int g = 0; g < ng; g++) {
            int ci = (g << 4) + em;
            bool cv = (ci < n);
            int ri = (g << 4) + (cv ? em : 0);        // g*16 < n always -> in-range
            uint2 rv = *(const uint2*)(rp + (size_t)ri * 8 + (kb >> 1));
            union { uint uu[2]; _Float16 h[4]; } up;
            up.uu[0] = rv.x; up.uu[1] = rv.y;
            float mk = cv ? 1.f : 0.f;
#pragma unroll
            for (int i = 0; i < 4; i++) {
                float x = (kb + i < H1) ? (float)up.h[i] * mk : 0.f;
                float x2 = x * x;
                s1[i] += x;
                s2[i] = fmaf(x, x, s2[i]);
                s3[i] = fmaf(x2, x, s3[i]);
                s4[i] = fmaf(x2, x2, s4[i]);
            }
        }

#pragma unroll
        for (int m = 1; m < 16; m <<= 1) {
#pragma unroll
            for (int i = 0; i < 4; i++) {
                s1[i] += __shfl_xor(s1[i], m, 64);
                s2[i] += __shfl_xor(s2[i], m, 64);
                s3[i] += __shfl_xor(s3[i], m, 64);
                s4[i] += __shfl_xor(s4[i], m, 64);
            }
        }

        if (em == 0) {                                // lanes 0,16,32,48 own kb..kb+3
            float inv = 1.0f / (float)(n > 1 ? n : 1);
#pragma unroll
            for (int i = 0; i < 4; i++) {
                int fj = kb + i;
                if (fj < H1) {
                    float a = s1[i] * inv, m2 = s2[i] * inv, m3 = s3[i] * inv, m4 = s4[i] * inv;
                    float a2 = a * a;
                    float var = m2 - a2;
                    float bb = sqrtf(1e-6f + fmaxf(var, 0.0f));
                    float c3 = m3 - 3.0f * a * m2 + 2.0f * a * a2;
                    float c4 = m4 - 4.0f * a * m3 + 6.0f * a2 * m2 - 3.0f * a2 * a2;
                    float ib = 1.0f / bb, ib2 = ib * ib;
                    feat[li][FXS + 1 + fj] = a;
                    feat[li][FXS + 1 + H1 + fj] = bb;
                    feat[li][FXS + 1 + 2 * H1 + fj] = c3 * ib * ib2;
                    feat[li][FXS + 1 + 3 * H1 + fj] = c4 * ib2 * ib2;
                }
            }
        }
        if (lane < FXS) {
            feat[li][lane] = x_s[(size_t)s * FXS + lane];
            feat[li][FXS + 1 + 4 * H1 + lane] = u[(size_t)batch_s[s] * FU + lane];
        }
        if (lane == 10) feat[li][FXS] = (float)n;
    }
    __syncthreads();

    for (int idx = t; idx < NPBLK * FXS; idx += 256) {
        int g = idx / FXS, j = idx - g * FXS;
        int s = nb + g;
        if (s < NSs) {
            float acc = sb3[j];
#pragma unroll
            for (int i = 0; i < H2; i++) acc = fmaf(feat[g][i], sW3[i * FXS + j], acc);
            l1s[g][j] = fmaxf(acc, 0.1f * acc);
        }
    }
    __syncthreads();

    for (int idx = t; idx < NPBLK * FXS; idx += 256) {
        int g = idx / FXS, j = idx - g * FXS;
        int s = nb + g;
        if (s < NSs) {
            float acc = sb4[j];
#pragma unroll
            for (int i = 0; i < FXS; i++) acc = fmaf(l1s[g][i], sW4[i * FXS + j], acc);
            out[(size_t)s * FXS + j] = acc;
        }
    }
}

extern "C" void kernel_launch(void* const* d_in, const int* in_sizes, int n_in,
                              void* d_out, int out_size, void* d_ws, size_t ws_size,
                              hipStream_t stream) {
    const float* x_s = (const float*)d_in[0];
    const float* x_t = (const float*)d_in[1];
    const float* ea  = (const float*)d_in[2];
    const float* u   = (const float*)d_in[3];
    const float* W1  = (const float*)d_in[4];
    const float* b1  = (const float*)d_in[5];
    const float* W2  = (const float*)d_in[6];
    const float* b2  = (const float*)d_in[7];
    const float* W3  = (const float*)d_in[8];
    const float* b3  = (const float*)d_in[9];
    const float* W4  = (const float*)d_in[10];
    const float* b4  = (const float*)d_in[11];
    const int* src   = (const int*)d_in[12];
    const int* tgt   = (const int*)d_in[13];
    const int* batch_s = (const int*)d_in[14];

    int NSs = in_sizes[0] / FXS;
    int E   = in_sizes[2] / FE;

    auto align_up = [](size_t x) { return (x + 255) & ~(size_t)255; };
    char* w = (char*)d_ws;
    int* cnt = (int*)w;     w += align_up((size_t)NSs * 4);
    int* offs = (int*)w;    w += align_up((size_t)NSs * 4);
    int* cursor = (int*)w;  w += align_up((size_t)NSs * 4);
    int* bsum = (int*)w;    w += 64 * 1024;
    uint* buf = (uint*)w;   // E * 32 bytes, node-sorted fp16 records

    hipMemsetAsync(cnt, 0, (size_t)NSs * 4, stream);
    hipMemsetAsync(cursor, 0, (size_t)NSs * 4, stream);

    k_hist<<<(E + 255) / 256, 256, 0, stream>>>(src, cnt, E);
    int nb = (NSs + SCAN_B - 1) / SCAN_B;
    k_scan1<<<nb, SCAN_B, 0, stream>>>(cnt, offs, bsum, NSs);
    k_scan2<<<1, SCAN_B, 0, stream>>>(bsum, nb);
    k_scan3<<<nb, SCAN_B, 0, stream>>>(offs, bsum, NSs);

    k_edge_mfma2<<<(E + TBE - 1) / TBE, TBE, 0, stream>>>(
        x_t, ea, W1, b1, W2, b2, src, tgt, offs, cursor, buf, E);

    k_moments3<<<(NSs + NPBLK - 1) / NPBLK, 256, 0, stream>>>(
        x_s, u, W3, b3, W4, b4, batch_s, cnt, offs, buf, (float*)d_out, NSs);
}